// Round 2
// baseline (1105.253 us; speedup 1.0000x reference)
//
#include <hip/hip_runtime.h>

// CG tensor-product iteration: per sample n, 34 (l1,l2,L) combos of
//   b[n,M,p,q] = sum_{i,j} x1_{l1}[n,i,p] * x2_{l2}[n,j,q] * C[i,j,M]
// packed into a (n, 39936) f32 row, keys (L,S) sorted, blocks concatenated.
// HBM-write-bound: 639 MB output vs ~8 MB input, ~7 GFLOP.
// This revision: one wave per sample, lane = (p, q-group-of-4) so every
// store is a contiguous 1KB/wave global_store_dwordx4 (was 256B dword).

namespace {

constexpr int NC = 34;

struct CInfo { int l1, l2, L, pbase, outbase, mstride; };
struct CTable { CInfo c[NC]; int packed_total; int outsize; };

constexpr CTable build_table() {
  CTable t{};
  // count blocks per (L, S) key; s index: 0 -> S=-1, 1 -> S=+1
  int nb[4][2] = {};
  for (int l1 = 0; l1 < 4; ++l1)
    for (int l2 = 0; l2 < 4; ++l2) {
      int lo = l1 > l2 ? l1 - l2 : l2 - l1;
      int hi = (l1 + l2 < 3) ? l1 + l2 : 3;
      for (int L = lo; L <= hi; ++L)
        nb[L][((l1 + l2 + L) & 1) ? 0 : 1]++;
    }
  // per-key offsets in sorted-key order (L asc, S=-1 before S=+1)
  int keyoff[4][2] = {};
  int off = 0;
  for (int L = 0; L < 4; ++L)
    for (int s = 0; s < 2; ++s) {
      keyoff[L][s] = off;
      off += (2 * L + 1) * 256 * nb[L][s];
    }
  t.outsize = off;
  // combos in reference iteration order; assign packed-coefficient bases
  // (16-float aligned) and output offsets.
  int blk[4][2] = {};
  int idx = 0, pb = 0;
  for (int l1 = 0; l1 < 4; ++l1)
    for (int l2 = 0; l2 < 4; ++l2) {
      int lo = l1 > l2 ? l1 - l2 : l2 - l1;
      int hi = (l1 + l2 < 3) ? l1 + l2 : 3;
      for (int L = lo; L <= hi; ++L) {
        int s = ((l1 + l2 + L) & 1) ? 0 : 1;
        pb = (pb + 15) & ~15;
        t.c[idx].l1 = l1; t.c[idx].l2 = l2; t.c[idx].L = L;
        t.c[idx].pbase = pb;
        t.c[idx].outbase = keyoff[L][s] + blk[L][s] * 256;
        t.c[idx].mstride = 256 * nb[L][s];
        blk[L][s]++;
        pb += (2 * l1 + 1) * (2 * l2 + 1) * (2 * L + 1);
        ++idx;
      }
    }
  t.packed_total = pb;
  return t;
}

constexpr CTable CTAB = build_table();
static_assert(CTAB.outsize == 39936, "output layout mismatch");
static_assert(CTAB.packed_total <= 4096, "packed cg exceeds 16KB");

// ---- coefficient pre-pack: gather cg[l1,l2,L,i,j,M] into contiguous,
// combo-major, (i,j,M)-ordered table in workspace (read order of main loop).
template <int CI>
__device__ __forceinline__ void pack_combo(const float* __restrict__ cg,
                                           float* __restrict__ cgp, int tid) {
  if constexpr (CI < NC) {
    constexpr CInfo c = CTAB.c[CI];
    constexpr int D2 = 2 * c.l2 + 1, DL = 2 * c.L + 1;
    constexpr int SZ = (2 * c.l1 + 1) * D2 * DL;
    for (int tt = tid; tt < SZ; tt += 256) {
      int M = tt % DL, ij = tt / DL;
      int j = ij % D2, i = ij / D2;
      cgp[c.pbase + tt] =
          cg[((((c.l1 * 4 + c.l2) * 4 + c.L) * 7 + i) * 7 + j) * 7 + M];
    }
    pack_combo<CI + 1>(cg, cgp, tid);
  }
}

__global__ void pack_cg_kernel(const float* __restrict__ cg,
                               float* __restrict__ cgp) {
  pack_combo<0>(cg, cgp, (int)threadIdx.x);
}

// ---- main loop: lane = (p = l>>2, qg = l&3); each lane computes the 4
// consecutive q columns [4*qg, 4*qg+4) and stores float4.
template <int CI>
__device__ __forceinline__ void run_combos(const float* __restrict__ cgp,
                                           const float (&x1r)[16],
                                           const float4* __restrict__ x2v4,
                                           int qg, float* __restrict__ outn) {
  if constexpr (CI < NC) {
    constexpr CInfo c = CTAB.c[CI];
    constexpr int D1 = 2 * c.l1 + 1, D2 = 2 * c.l2 + 1, DL = 2 * c.L + 1;
    constexpr int R1 = c.l1 * c.l1, R2 = c.l2 * c.l2;  // row bases: l^2
    float4 xv[D2];
#pragma unroll
    for (int j = 0; j < D2; ++j) xv[j] = x2v4[(R2 + j) * 4 + qg];
    float4 acc[DL];
#pragma unroll
    for (int M = 0; M < DL; ++M) acc[M] = float4{0.f, 0.f, 0.f, 0.f};
#pragma unroll
    for (int i = 0; i < D1; ++i) {
      const float a = x1r[R1 + i];
#pragma unroll
      for (int j = 0; j < D2; ++j) {
        float4 ab;
        ab.x = a * xv[j].x; ab.y = a * xv[j].y;
        ab.z = a * xv[j].z; ab.w = a * xv[j].w;
#pragma unroll
        for (int M = 0; M < DL; ++M) {
          const float cc = cgp[c.pbase + (i * D2 + j) * DL + M];
          acc[M].x = fmaf(cc, ab.x, acc[M].x);
          acc[M].y = fmaf(cc, ab.y, acc[M].y);
          acc[M].z = fmaf(cc, ab.z, acc[M].z);
          acc[M].w = fmaf(cc, ab.w, acc[M].w);
        }
      }
    }
#pragma unroll
    for (int M = 0; M < DL; ++M)
      *reinterpret_cast<float4*>(outn + c.outbase + M * c.mstride) = acc[M];
    run_combos<CI + 1>(cgp, x1r, x2v4, qg, outn);
  }
}

__global__ __launch_bounds__(256) void cg_main(
    const float* __restrict__ x1_0, const float* __restrict__ x2_0,
    const float* __restrict__ x1_1, const float* __restrict__ x2_1,
    const float* __restrict__ x1_2, const float* __restrict__ x2_2,
    const float* __restrict__ x1_3, const float* __restrict__ x2_3,
    const float* __restrict__ cgp_, float* __restrict__ out, int nsamp) {
  const float* cgp = (const float*)__builtin_assume_aligned(cgp_, 256);
  // row = lm index (l^2 + i), col = Q; 16B-aligned so rows read as float4
  __shared__ __align__(16) float x1s[4][16][16];
  __shared__ __align__(16) float x2s[4][16][16];
  const int tid = (int)threadIdx.x;
  const int n0 = (int)blockIdx.x * 4;
  // cooperatively stage 4 samples' inputs (4*2*256 floats, coalesced rows)
#pragma unroll
  for (int k = 0; k < 4; ++k) {
    const int idx = tid + 256 * k;  // flattened [s][r][c]
    const int s = idx >> 8, rem = idx & 255, r = rem >> 4, cc = rem & 15;
    const int n = n0 + s;
    if (n < nsamp) {
      const float* s1; const float* s2; int ri;
      if (r < 1)      { s1 = x1_0 + n * 16;  s2 = x2_0 + n * 16;  ri = r; }
      else if (r < 4) { s1 = x1_1 + n * 48;  s2 = x2_1 + n * 48;  ri = r - 1; }
      else if (r < 9) { s1 = x1_2 + n * 80;  s2 = x2_2 + n * 80;  ri = r - 4; }
      else            { s1 = x1_3 + n * 112; s2 = x2_3 + n * 112; ri = r - 9; }
      x1s[s][r][cc] = s1[ri * 16 + cc];
      x2s[s][r][cc] = s2[ri * 16 + cc];
    }
  }
  __syncthreads();
  // one wave per sample
  const int s = tid >> 6, l = tid & 63;
  const int n = n0 + s;
  if (n >= nsamp) return;
  const int p = l >> 2, qg = l & 3;
  float x1r[16];
#pragma unroll
  for (int k = 0; k < 16; ++k) x1r[k] = x1s[s][k][p];
  const float4* x2v4 = reinterpret_cast<const float4*>(&x2s[s][0][0]);
  // lane's byte base within the sample row: column = p*16 + 4*qg = 4*l
  float* outn = out + (size_t)n * (size_t)CTAB.outsize + 4 * l;
  run_combos<0>(cgp, x1r, x2v4, qg, outn);
}

}  // namespace

extern "C" void kernel_launch(void* const* d_in, const int* in_sizes, int n_in,
                              void* d_out, int out_size, void* d_ws,
                              size_t ws_size, hipStream_t stream) {
  const float* x1[4];
  const float* x2[4];
  // setup_inputs() dict order is interleaved (x1_l0, x2_l0, x1_l1, ...);
  // detect vs grouped (x1_l0..x1_l3, x2_l0..) via sizes.
  if (in_sizes[1] == in_sizes[0]) {
    for (int l = 0; l < 4; ++l) {
      x1[l] = (const float*)d_in[2 * l];
      x2[l] = (const float*)d_in[2 * l + 1];
    }
  } else {
    for (int l = 0; l < 4; ++l) {
      x1[l] = (const float*)d_in[l];
      x2[l] = (const float*)d_in[4 + l];
    }
  }
  const float* cg = (const float*)d_in[8];
  float* out = (float*)d_out;
  float* cgp = (float*)d_ws;  // packed coefficients (~16 KB)

  const int n = in_sizes[0] / 16;  // x?_l0 is (n, 1, 16)
  const int nblocks = (n + 3) / 4;

  pack_cg_kernel<<<1, 256, 0, stream>>>(cg, cgp);
  cg_main<<<nblocks, 256, 0, stream>>>(x1[0], x2[0], x1[1], x2[1], x1[2],
                                       x2[2], x1[3], x2[3], cgp, out, n);
}

// Round 3
// 165.750 us; speedup vs baseline: 6.6682x; 6.6682x over previous
//
#include <hip/hip_runtime.h>

// CG tensor-product iteration: per sample n, 34 (l1,l2,L) combos of
//   b[n,M,p,q] = sum_{i,j} x1_{l1}[n,i,p] * x2_{l2}[n,j,q] * C[i,j,M]
// packed into a (n, 39936) f32 row, keys (L,S) sorted, blocks concatenated.
// HBM-write-bound: 639 MB output vs ~8 MB input, ~7 GFLOP.
//
// Round-2 post-mortem: float4 accumulators spilled (VGPR=256, ~880MB scratch
// traffic). This revision: round-1 scalar compute (lean registers) + per-combo
// LDS staging + cooperative float4 flush (1KB/wave-inst stores).

namespace {

constexpr int NC = 34;

struct CInfo { int l1, l2, L, pbase, outbase, mstride; };
struct CTable { CInfo c[NC]; int packed_total; int outsize; };

constexpr CTable build_table() {
  CTable t{};
  // count blocks per (L, S) key; s index: 0 -> S=-1, 1 -> S=+1
  int nb[4][2] = {};
  for (int l1 = 0; l1 < 4; ++l1)
    for (int l2 = 0; l2 < 4; ++l2) {
      int lo = l1 > l2 ? l1 - l2 : l2 - l1;
      int hi = (l1 + l2 < 3) ? l1 + l2 : 3;
      for (int L = lo; L <= hi; ++L)
        nb[L][((l1 + l2 + L) & 1) ? 0 : 1]++;
    }
  // per-key offsets in sorted-key order (L asc, S=-1 before S=+1)
  int keyoff[4][2] = {};
  int off = 0;
  for (int L = 0; L < 4; ++L)
    for (int s = 0; s < 2; ++s) {
      keyoff[L][s] = off;
      off += (2 * L + 1) * 256 * nb[L][s];
    }
  t.outsize = off;
  // combos in reference iteration order; assign packed-coefficient bases
  // (16-float aligned) and output offsets.
  int blk[4][2] = {};
  int idx = 0, pb = 0;
  for (int l1 = 0; l1 < 4; ++l1)
    for (int l2 = 0; l2 < 4; ++l2) {
      int lo = l1 > l2 ? l1 - l2 : l2 - l1;
      int hi = (l1 + l2 < 3) ? l1 + l2 : 3;
      for (int L = lo; L <= hi; ++L) {
        int s = ((l1 + l2 + L) & 1) ? 0 : 1;
        pb = (pb + 15) & ~15;
        t.c[idx].l1 = l1; t.c[idx].l2 = l2; t.c[idx].L = L;
        t.c[idx].pbase = pb;
        t.c[idx].outbase = keyoff[L][s] + blk[L][s] * 256;
        t.c[idx].mstride = 256 * nb[L][s];
        blk[L][s]++;
        pb += (2 * l1 + 1) * (2 * l2 + 1) * (2 * L + 1);
        ++idx;
      }
    }
  t.packed_total = pb;
  return t;
}

constexpr CTable CTAB = build_table();
static_assert(CTAB.outsize == 39936, "output layout mismatch");
static_assert(CTAB.packed_total <= 4096, "packed cg exceeds 16KB");

// ---- coefficient pre-pack: gather cg[l1,l2,L,i,j,M] into contiguous,
// combo-major, (i,j,M)-ordered table in workspace (read order of main loop).
template <int CI>
__device__ __forceinline__ void pack_combo(const float* __restrict__ cg,
                                           float* __restrict__ cgp, int tid) {
  if constexpr (CI < NC) {
    constexpr CInfo c = CTAB.c[CI];
    constexpr int D2 = 2 * c.l2 + 1, DL = 2 * c.L + 1;
    constexpr int SZ = (2 * c.l1 + 1) * D2 * DL;
    for (int tt = tid; tt < SZ; tt += 256) {
      int M = tt % DL, ij = tt / DL;
      int j = ij % D2, i = ij / D2;
      cgp[c.pbase + tt] =
          cg[((((c.l1 * 4 + c.l2) * 4 + c.L) * 7 + i) * 7 + j) * 7 + M];
    }
    pack_combo<CI + 1>(cg, cgp, tid);
  }
}

__global__ void pack_cg_kernel(const float* __restrict__ cg,
                               float* __restrict__ cgp) {
  pack_combo<0>(cg, cgp, (int)threadIdx.x);
}

// ---- main: one block per sample, thread = (p = tid>>4, q = tid&15).
// Scalar accumulation (low VGPR); per-combo LDS stage + float4 flush.
template <int CI>
__device__ __forceinline__ void run_combos(const float* __restrict__ cgp,
                                           const float (&x1r)[16],
                                           const float (&x2r)[16],
                                           float* __restrict__ stage,
                                           float* __restrict__ outn,
                                           int tid) {
  if constexpr (CI < NC) {
    constexpr CInfo c = CTAB.c[CI];
    constexpr int D1 = 2 * c.l1 + 1, D2 = 2 * c.l2 + 1, DL = 2 * c.L + 1;
    constexpr int R1 = c.l1 * c.l1, R2 = c.l2 * c.l2;  // row bases: l^2
    float acc[DL];
#pragma unroll
    for (int M = 0; M < DL; ++M) acc[M] = 0.f;
#pragma unroll
    for (int i = 0; i < D1; ++i) {
#pragma unroll
      for (int j = 0; j < D2; ++j) {
        const float ab = x1r[R1 + i] * x2r[R2 + j];
#pragma unroll
        for (int M = 0; M < DL; ++M)
          acc[M] = fmaf(cgp[c.pbase + (i * D2 + j) * DL + M], ab, acc[M]);
      }
    }
    // stage scalar results (conflict-free ds_write_b32), then flush as
    // float4: wave w writes row M = w + 4k (1KB contiguous per wave-inst).
    float* buf = stage + (CI & 1) * 1792;
#pragma unroll
    for (int M = 0; M < DL; ++M) buf[M * 256 + tid] = acc[M];
    __syncthreads();
    const unsigned w = (unsigned)tid >> 6, l = (unsigned)tid & 63u;
#pragma unroll
    for (int k = 0; k < (DL + 3) / 4; ++k) {
      const unsigned M = w + 4u * k;
      if (M < (unsigned)DL) {
        const float4 v = *reinterpret_cast<const float4*>(buf + M * 256 + 4 * l);
        *reinterpret_cast<float4*>(outn + c.outbase + M * c.mstride + 4 * l) = v;
      }
    }
    // no second barrier: next combo uses the other stage buffer, whose last
    // readers (flush of combo CI-1) all passed this barrier already.
    run_combos<CI + 1>(cgp, x1r, x2r, stage, outn, tid);
  }
}

__global__ __launch_bounds__(256) void cg_main(
    const float* __restrict__ x1_0, const float* __restrict__ x2_0,
    const float* __restrict__ x1_1, const float* __restrict__ x2_1,
    const float* __restrict__ x1_2, const float* __restrict__ x2_2,
    const float* __restrict__ x1_3, const float* __restrict__ x2_3,
    const float* __restrict__ cgp_, float* __restrict__ out) {
  const float* cgp = (const float*)__builtin_assume_aligned(cgp_, 256);
  __shared__ float x1s[16][16];  // row = lm index (l^2 + i), col = Q
  __shared__ float x2s[16][16];
  __shared__ __align__(16) float stage[2 * 1792];  // double-buffered flush
  const int tid = (int)threadIdx.x;
  const int n = (int)blockIdx.x;
  const int r = tid >> 4, col = tid & 15;
  // stage this sample's 2*256 input floats (each thread: 1 x1 + 1 x2 elem)
  const float* s1; const float* s2; int ri;
  if (r < 1)      { s1 = x1_0 + n * 16;  s2 = x2_0 + n * 16;  ri = r; }
  else if (r < 4) { s1 = x1_1 + n * 48;  s2 = x2_1 + n * 48;  ri = r - 1; }
  else if (r < 9) { s1 = x1_2 + n * 80;  s2 = x2_2 + n * 80;  ri = r - 4; }
  else            { s1 = x1_3 + n * 112; s2 = x2_3 + n * 112; ri = r - 9; }
  x1s[r][col] = s1[ri * 16 + col];
  x2s[r][col] = s2[ri * 16 + col];
  __syncthreads();
  // hoist this thread's columns into registers (compile-time indexed)
  float x1r[16], x2r[16];
#pragma unroll
  for (int k = 0; k < 16; ++k) {
    x1r[k] = x1s[k][r];    // p = r
    x2r[k] = x2s[k][col];  // q = col
  }
  float* outn = out + (size_t)n * (size_t)CTAB.outsize;
  run_combos<0>(cgp, x1r, x2r, stage, outn, tid);
}

}  // namespace

extern "C" void kernel_launch(void* const* d_in, const int* in_sizes, int n_in,
                              void* d_out, int out_size, void* d_ws,
                              size_t ws_size, hipStream_t stream) {
  const float* x1[4];
  const float* x2[4];
  // setup_inputs() dict order is interleaved (x1_l0, x2_l0, x1_l1, ...);
  // detect vs grouped (x1_l0..x1_l3, x2_l0..) via sizes.
  if (in_sizes[1] == in_sizes[0]) {
    for (int l = 0; l < 4; ++l) {
      x1[l] = (const float*)d_in[2 * l];
      x2[l] = (const float*)d_in[2 * l + 1];
    }
  } else {
    for (int l = 0; l < 4; ++l) {
      x1[l] = (const float*)d_in[l];
      x2[l] = (const float*)d_in[4 + l];
    }
  }
  const float* cg = (const float*)d_in[8];
  float* out = (float*)d_out;
  float* cgp = (float*)d_ws;  // packed coefficients (~16 KB)

  const int n = in_sizes[0] / 16;  // x?_l0 is (n, 1, 16)

  pack_cg_kernel<<<1, 256, 0, stream>>>(cg, cgp);
  cg_main<<<n, 256, 0, stream>>>(x1[0], x2[0], x1[1], x2[1], x1[2], x2[2],
                                 x1[3], x2[3], cgp, out);
}